// Round 2
// baseline (1585.136 us; speedup 1.0000x reference)
//
#include <hip/hip_runtime.h>
#include <stdint.h>

// RWKV-4 block: B=8, T=2048, C=1024, DIM_FFN=4096, fp32 in/out, bf16 MFMA internally.
#define B_ 8
#define T_ 2048
#define C_ 1024
#define F_ 4096
#define M_ (B_*T_)   // 16384 rows

typedef __attribute__((ext_vector_type(8))) short bf16x8;   // 8 bf16 (4 VGPRs) MFMA A/B frag
typedef __attribute__((ext_vector_type(4))) float f32x4;    // MFMA C/D frag

static __device__ __forceinline__ unsigned short f2bf(float f) {
    union { float f; unsigned u; } v; v.f = f;
    unsigned r = v.u + 0x7fffu + ((v.u >> 16) & 1u);  // RNE
    return (unsigned short)(r >> 16);
}
static __device__ __forceinline__ float bf2f(unsigned short h) {
    union { unsigned u; float f; } v; v.u = ((unsigned)h) << 16;
    return v.f;
}

// ---------------------------------------------------------------------------
// Weight conversion fp32 -> bf16 into one packed ws region (13M elems, 26MB).
// dst element layout: [Wk 1M][Wv 1M][Wr 1M][Wo 1M][Wrec 1M][Wkey 4M][Wval 4M]
// ---------------------------------------------------------------------------
struct WSrc { const float* p[7]; };

__global__ __launch_bounds__(256) void k_convert(WSrc w, unsigned short* __restrict__ dst) {
    size_t e = ((size_t)blockIdx.x * 256 + threadIdx.x) * 4;
    int seg = (int)(e >> 20);
    const float* s; size_t off;
    if (seg < 5)      { s = w.p[seg]; off = e - ((size_t)seg << 20); }
    else if (seg < 9) { s = w.p[5];   off = e - (5ull << 20); }
    else              { s = w.p[6];   off = e - (9ull << 20); }
    float4 v = *(const float4*)(s + off);
    ushort4 o;
    o.x = f2bf(v.x); o.y = f2bf(v.y); o.z = f2bf(v.z); o.w = f2bf(v.w);
    *(ushort4*)(dst + e) = o;
}

// ---------------------------------------------------------------------------
// Fused LayerNorm + time_shift + token-mix. One block per row m = b*T+t.
// h = LN(x[m]), hh = (t>0) ? LN(x[m-1]) : 0; out = h*tm + hh*(1-tm). bf16 out.
// ---------------------------------------------------------------------------
template<int THREE>
__global__ __launch_bounds__(256) void k_ln_mix(
    const float* __restrict__ xin, const float* __restrict__ lw, const float* __restrict__ lb,
    const float* __restrict__ tk, const float* __restrict__ tv, const float* __restrict__ tr,
    unsigned short* __restrict__ ok, unsigned short* __restrict__ ov, unsigned short* __restrict__ orr)
{
    __shared__ float sred[4][4];
    const int m = blockIdx.x;
    const int t = m & (T_ - 1);
    const int tid = threadIdx.x;
    const int col0 = tid * 4;

    const float4 xc = *(const float4*)(xin + (size_t)m * C_ + col0);
    float4 xp = make_float4(0.f, 0.f, 0.f, 0.f);
    if (t > 0) xp = *(const float4*)(xin + (size_t)(m - 1) * C_ + col0);

    float s1 = xc.x + xc.y + xc.z + xc.w;
    float s2 = xc.x*xc.x + xc.y*xc.y + xc.z*xc.z + xc.w*xc.w;
    float s3 = xp.x + xp.y + xp.z + xp.w;
    float s4 = xp.x*xp.x + xp.y*xp.y + xp.z*xp.z + xp.w*xp.w;
    #pragma unroll
    for (int off = 32; off > 0; off >>= 1) {
        s1 += __shfl_down(s1, off);
        s2 += __shfl_down(s2, off);
        s3 += __shfl_down(s3, off);
        s4 += __shfl_down(s4, off);
    }
    const int wave = tid >> 6, lane = tid & 63;
    if (lane == 0) { sred[0][wave]=s1; sred[1][wave]=s2; sred[2][wave]=s3; sred[3][wave]=s4; }
    __syncthreads();
    const float S1 = sred[0][0]+sred[0][1]+sred[0][2]+sred[0][3];
    const float S2 = sred[1][0]+sred[1][1]+sred[1][2]+sred[1][3];
    const float S3 = sred[2][0]+sred[2][1]+sred[2][2]+sred[2][3];
    const float S4 = sred[3][0]+sred[3][1]+sred[3][2]+sred[3][3];

    const float inv = 1.0f / (float)C_;
    const float muc = S1 * inv;
    const float rc  = rsqrtf(S2 * inv - muc * muc + 1e-5f);
    const float mup = S3 * inv;
    const float rp  = rsqrtf(S4 * inv - mup * mup + 1e-5f);

    const float xcv[4] = {xc.x, xc.y, xc.z, xc.w};
    const float xpv[4] = {xp.x, xp.y, xp.z, xp.w};
    unsigned short rk[4], rv[4], rr[4];
    #pragma unroll
    for (int i = 0; i < 4; ++i) {
        const int col = col0 + i;
        const float w_ = lw[col], b_ = lb[col];
        const float h  = (xcv[i] - muc) * rc * w_ + b_;
        const float hh = (t > 0) ? (xpv[i] - mup) * rp * w_ + b_ : 0.f;
        const float ak = tk[col];
        rk[i] = f2bf(h * ak + hh * (1.f - ak));
        if (THREE) { const float av = tv[col]; rv[i] = f2bf(h * av + hh * (1.f - av)); }
        const float ar = tr[col];
        rr[i] = f2bf(h * ar + hh * (1.f - ar));
    }
    const size_t o = (size_t)m * C_ + col0;
    ushort4 u;
    u.x = rk[0]; u.y = rk[1]; u.z = rk[2]; u.w = rk[3];
    *(ushort4*)(ok + o) = u;
    if (THREE) {
        u.x = rv[0]; u.y = rv[1]; u.z = rv[2]; u.w = rv[3];
        *(ushort4*)(ov + o) = u;
    }
    u.x = rr[0]; u.y = rr[1]; u.z = rr[2]; u.w = rr[3];
    *(ushort4*)(orr + o) = u;
}

// ---------------------------------------------------------------------------
// WKV serial scan: one thread per (b,c), loop over t. Fuses p = sr * y.
// k,v,sr bf16 in; p bf16 out. State fp32.
// ---------------------------------------------------------------------------
__global__ __launch_bounds__(256) void k_wkv(
    const unsigned short* __restrict__ k16, const unsigned short* __restrict__ v16,
    const unsigned short* __restrict__ sr,
    const float* __restrict__ tdec, const float* __restrict__ tfirst,
    unsigned short* __restrict__ p)
{
    const int g = blockIdx.x * 256 + threadIdx.x;   // 0..8191
    const int b = g >> 10;
    const int c = g & (C_ - 1);
    const float w = -__expf(tdec[c]);
    const float u = tfirst[c];
    float aa = 0.f, bb = 0.f, pp = -1e38f;
    const size_t base = (size_t)b * T_ * C_ + c;
    for (int t = 0; t < T_; ++t) {
        const size_t idx = base + (size_t)t * C_;
        const float kt = bf2f(k16[idx]);
        const float vt = bf2f(v16[idx]);
        float ww = u + kt;
        float qq = fmaxf(pp, ww);
        float e1 = __expf(pp - qq);
        float e2 = __expf(ww - qq);
        float y = (e1 * aa + e2 * vt) / (e1 * bb + e2);
        float ww2 = pp + w;
        float qq2 = fmaxf(ww2, kt);
        float e1b = __expf(ww2 - qq2);
        float e2b = __expf(kt - qq2);
        aa = e1b * aa + e2b * vt;
        bb = e1b * bb + e2b;
        pp = qq2;
        p[idx] = f2bf(bf2f(sr[idx]) * y);
    }
}

// ---------------------------------------------------------------------------
// bf16 MFMA GEMM: out[m,n] = sum_k A[m,k] * Bw[n,k]  (A:[M,K] ld=lda, Bw ld=ldb)
// 128x128 block tile, 4 waves (2x2 of 64x64 wave tiles), BK=32, 16x16x32 MFMA.
// EPI: 0 = bf16 store; 1 = sigmoid->bf16; 2 = resid + acc -> fp32;
//      3 = relu(acc)^2 -> bf16; 4 = outF += bf16(mul)*acc (fp32 rmw)
// ---------------------------------------------------------------------------
template<int EPI>
__global__ __launch_bounds__(256) void k_gemm(
    const unsigned short* __restrict__ A, int lda,
    const unsigned short* __restrict__ Bw, int ldb,
    int K, int N,
    float* __restrict__ outF, unsigned short* __restrict__ outH,
    const float* __restrict__ resid, const unsigned short* __restrict__ mul)
{
    __shared__ unsigned short As[128 * 32];
    __shared__ unsigned short Bs[128 * 32];
    const int tid  = threadIdx.x;
    const int wave = tid >> 6, lane = tid & 63;
    const int quad = lane >> 4, l16 = lane & 15;
    const int m0 = blockIdx.x * 128, n0 = blockIdx.y * 128;
    const int wm = (wave >> 1) * 64, wn = (wave & 1) * 64;

    f32x4 acc[4][4];
    const f32x4 zero = {0.f, 0.f, 0.f, 0.f};
    #pragma unroll
    for (int i = 0; i < 4; ++i)
        #pragma unroll
        for (int j = 0; j < 4; ++j) acc[i][j] = zero;

    const int row_a = tid >> 2;          // 0..63
    const int col_a = (tid & 3) * 8;     // 0,8,16,24

    for (int kt = 0; kt < K; kt += 32) {
        // stage A,B tiles (each thread: 2 x 16B per matrix), contiguous LDS writes
        *(uint4*)(As + row_a * 32 + col_a)        = *(const uint4*)(A  + (size_t)(m0 + row_a) * lda + kt + col_a);
        *(uint4*)(As + (row_a + 64) * 32 + col_a) = *(const uint4*)(A  + (size_t)(m0 + row_a + 64) * lda + kt + col_a);
        *(uint4*)(Bs + row_a * 32 + col_a)        = *(const uint4*)(Bw + (size_t)(n0 + row_a) * ldb + kt + col_a);
        *(uint4*)(Bs + (row_a + 64) * 32 + col_a) = *(const uint4*)(Bw + (size_t)(n0 + row_a + 64) * ldb + kt + col_a);
        __syncthreads();

        bf16x8 af[4], bfr[4];
        #pragma unroll
        for (int i = 0; i < 4; ++i) {
            af[i]  = *(const bf16x8*)(As + (wm + i * 16 + l16) * 32 + quad * 8);
            bfr[i] = *(const bf16x8*)(Bs + (wn + i * 16 + l16) * 32 + quad * 8);
        }
        #pragma unroll
        for (int i = 0; i < 4; ++i)
            #pragma unroll
            for (int j = 0; j < 4; ++j)
                acc[i][j] = __builtin_amdgcn_mfma_f32_16x16x32_bf16(af[i], bfr[j], acc[i][j], 0, 0, 0);
        __syncthreads();
    }

    // epilogue: C/D layout row = quad*4 + reg, col = l16
    #pragma unroll
    for (int i = 0; i < 4; ++i) {
        const int rowb = m0 + wm + i * 16 + quad * 4;
        #pragma unroll
        for (int j = 0; j < 4; ++j) {
            const int col = n0 + wn + j * 16 + l16;
            #pragma unroll
            for (int r = 0; r < 4; ++r) {
                const size_t idx = (size_t)(rowb + r) * N + col;
                const float v = acc[i][j][r];
                if (EPI == 0)      outH[idx] = f2bf(v);
                else if (EPI == 1) outH[idx] = f2bf(1.f / (1.f + __expf(-v)));
                else if (EPI == 2) outF[idx] = resid[idx] + v;
                else if (EPI == 3) { const float z = v > 0.f ? v : 0.f; outH[idx] = f2bf(z * z); }
                else               outF[idx] = outF[idx] + bf2f(mul[idx]) * v;
            }
        }
    }
}

// ---------------------------------------------------------------------------
// Workspace layout (peak 154 MB, every byte written before read each launch):
//   [0,32)MB    xk   -> v    -> xk2
//   [32,64)     xv   -> p    -> tmp (FFN chunk)
//   [64,96)     xr   -> k    -> xr2
//   [96,128)    sr   -> s2
//   [128,154)   bf16 weights (13M elems)
//   x1 lives in d_out (fp32), FFN chunks accumulate into d_out.
// ---------------------------------------------------------------------------
extern "C" void kernel_launch(void* const* d_in, const int* in_sizes, int n_in,
                              void* d_out, int out_size, void* d_ws, size_t ws_size,
                              hipStream_t stream)
{
    const float* x      = (const float*)d_in[0];
    const float* ln1w   = (const float*)d_in[1];
    const float* ln1b   = (const float*)d_in[2];
    const float* ln2w   = (const float*)d_in[3];
    const float* ln2b   = (const float*)d_in[4];
    const float* atk    = (const float*)d_in[5];
    const float* atv    = (const float*)d_in[6];
    const float* atr    = (const float*)d_in[7];
    const float* tdec   = (const float*)d_in[8];
    const float* tfirst = (const float*)d_in[9];
    const float* Wk     = (const float*)d_in[10];
    const float* Wv     = (const float*)d_in[11];
    const float* Wr     = (const float*)d_in[12];
    const float* Wo     = (const float*)d_in[13];
    const float* ftk    = (const float*)d_in[14];
    const float* ftr    = (const float*)d_in[15];
    const float* Wkey   = (const float*)d_in[16];
    const float* Wrec   = (const float*)d_in[17];
    const float* Wval   = (const float*)d_in[18];
    float* out = (float*)d_out;

    char* ws = (char*)d_ws;
    const size_t MB = 1ull << 20;
    unsigned short* xk  = (unsigned short*)(ws + 0 * MB);
    unsigned short* xv  = (unsigned short*)(ws + 32 * MB);
    unsigned short* xr  = (unsigned short*)(ws + 64 * MB);
    unsigned short* sr  = (unsigned short*)(ws + 96 * MB);
    unsigned short* wb  = (unsigned short*)(ws + 128 * MB);
    unsigned short* kb  = xr;   // k bf16 overwrites xr (dead after r-GEMM)
    unsigned short* vb  = xk;   // v bf16 overwrites xk (dead after k-GEMM)
    unsigned short* p   = xv;   // p overwrites xv (dead after v-GEMM)
    unsigned short* xk2 = xk;
    unsigned short* xr2 = xr;
    unsigned short* s2  = sr;
    unsigned short* tmp = xv;   // FFN chunk buffer (p dead after Wo-GEMM)

    unsigned short* Wk_b   = wb;
    unsigned short* Wv_b   = wb + 1 * (1u << 20);
    unsigned short* Wr_b   = wb + 2 * (1u << 20);
    unsigned short* Wo_b   = wb + 3 * (1u << 20);
    unsigned short* Wrec_b = wb + 4 * (1u << 20);
    unsigned short* Wkey_b = wb + 5 * (1u << 20);
    unsigned short* Wval_b = wb + 9 * (1u << 20);

    // 1) weights -> bf16
    WSrc wsrc; wsrc.p[0]=Wk; wsrc.p[1]=Wv; wsrc.p[2]=Wr; wsrc.p[3]=Wo;
    wsrc.p[4]=Wrec; wsrc.p[5]=Wkey; wsrc.p[6]=Wval;
    k_convert<<<dim3(13312), dim3(256), 0, stream>>>(wsrc, wb);

    // 2) LN1 + time-shift mix -> xk, xv, xr (bf16)
    k_ln_mix<1><<<dim3(M_), dim3(256), 0, stream>>>(x, ln1w, ln1b, atk, atv, atr, xk, xv, xr);

    // 3) sr = sigmoid(xr @ Wr^T) first (frees xr), then k, v (bf16)
    k_gemm<1><<<dim3(128, 8), dim3(256), 0, stream>>>(xr, 1024, Wr_b, 1024, 1024, 1024, (float*)nullptr, sr, (const float*)nullptr, (const unsigned short*)nullptr);
    k_gemm<0><<<dim3(128, 8), dim3(256), 0, stream>>>(xk, 1024, Wk_b, 1024, 1024, 1024, (float*)nullptr, kb, (const float*)nullptr, (const unsigned short*)nullptr);
    k_gemm<0><<<dim3(128, 8), dim3(256), 0, stream>>>(xv, 1024, Wv_b, 1024, 1024, 1024, (float*)nullptr, vb, (const float*)nullptr, (const unsigned short*)nullptr);

    // 4) WKV scan, fused p = sr * y (bf16)
    k_wkv<<<dim3(32), dim3(256), 0, stream>>>(kb, vb, sr, tdec, tfirst, p);

    // 5) x1 = x + p @ Wo^T -> d_out (fp32)
    k_gemm<2><<<dim3(128, 8), dim3(256), 0, stream>>>(p, 1024, Wo_b, 1024, 1024, 1024, out, (unsigned short*)nullptr, x, (const unsigned short*)nullptr);

    // 6) LN2 + time-shift mix -> xk2, xr2 (bf16)
    k_ln_mix<0><<<dim3(M_), dim3(256), 0, stream>>>(out, ln2w, ln2b, ftk, (const float*)nullptr, ftr, xk2, (unsigned short*)nullptr, xr2);

    // 7) s2 = sigmoid(xr2 @ Wrec^T) (bf16)
    k_gemm<1><<<dim3(128, 8), dim3(256), 0, stream>>>(xr2, 1024, Wrec_b, 1024, 1024, 1024, (float*)nullptr, s2, (const float*)nullptr, (const unsigned short*)nullptr);

    // 8) FFN chunked over F (4 x 1024): out += s2 * (relu(xk2@Wkey_f^T)^2 @ Wval_f^T)
    for (int f = 0; f < 4; ++f) {
        const unsigned short* WkeyF = Wkey_b + (size_t)f * 1024 * 1024;  // rows f*1024..
        const unsigned short* WvalF = Wval_b + (size_t)f * 1024;         // col offset, ld=4096
        k_gemm<3><<<dim3(128, 8), dim3(256), 0, stream>>>(xk2, 1024, WkeyF, 1024, 1024, 1024, (float*)nullptr, tmp, (const float*)nullptr, (const unsigned short*)nullptr);
        k_gemm<4><<<dim3(128, 8), dim3(256), 0, stream>>>(tmp, 1024, WvalF, 4096, 1024, 1024, out, (unsigned short*)nullptr, (const float*)nullptr, s2);
    }
}

// Round 3
// 1414.460 us; speedup vs baseline: 1.1207x; 1.1207x over previous
//
#include <hip/hip_runtime.h>
#include <stdint.h>

// RWKV-4 block: B=8, T=2048, C=1024, DIM_FFN=4096, fp32 in/out, bf16 MFMA internally.
#define B_ 8
#define T_ 2048
#define C_ 1024
#define F_ 4096
#define M_ (B_*T_)   // 16384 rows

typedef __attribute__((ext_vector_type(8))) short bf16x8;   // MFMA A/B frag (4 VGPRs)
typedef __attribute__((ext_vector_type(4))) float f32x4;    // MFMA C/D frag
typedef __attribute__((ext_vector_type(8))) unsigned short ushort8;

static __device__ __forceinline__ unsigned short f2bf(float f) {
    union { float f; unsigned u; } v; v.f = f;
    unsigned r = v.u + 0x7fffu + ((v.u >> 16) & 1u);  // RNE
    return (unsigned short)(r >> 16);
}
static __device__ __forceinline__ float bf2f(unsigned short h) {
    union { unsigned u; float f; } v; v.u = ((unsigned)h) << 16;
    return v.f;
}

// async global->LDS, 16B/lane, wave-uniform LDS base + lane*16 (m97 pattern)
#define GLDS16(gp, lp) __builtin_amdgcn_global_load_lds( \
    (const __attribute__((address_space(1))) unsigned int*)(gp), \
    (__attribute__((address_space(3))) unsigned int*)(lp), 16, 0, 0)

// ---------------------------------------------------------------------------
// Weight conversion fp32 -> bf16 into one packed ws region (13M elems, 26MB).
// dst element layout: [Wk 1M][Wv 1M][Wr 1M][Wo 1M][Wrec 1M][Wkey 4M][Wval 4M]
// ---------------------------------------------------------------------------
struct WSrc { const float* p[7]; };

__global__ __launch_bounds__(256) void k_convert(WSrc w, unsigned short* __restrict__ dst) {
    size_t e = ((size_t)blockIdx.x * 256 + threadIdx.x) * 4;
    int seg = (int)(e >> 20);
    const float* s; size_t off;
    if (seg < 5)      { s = w.p[seg]; off = e - ((size_t)seg << 20); }
    else if (seg < 9) { s = w.p[5];   off = e - (5ull << 20); }
    else              { s = w.p[6];   off = e - (9ull << 20); }
    float4 v = *(const float4*)(s + off);
    ushort4 o;
    o.x = f2bf(v.x); o.y = f2bf(v.y); o.z = f2bf(v.z); o.w = f2bf(v.w);
    *(ushort4*)(dst + e) = o;
}

// ---------------------------------------------------------------------------
// Fused LayerNorm + time_shift + token-mix. One block per row m = b*T+t.
// h = LN(x[m]), hh = (t>0) ? LN(x[m-1]) : 0; out = h*tm + hh*(1-tm). bf16 out.
// ---------------------------------------------------------------------------
template<int THREE>
__global__ __launch_bounds__(256) void k_ln_mix(
    const float* __restrict__ xin, const float* __restrict__ lw, const float* __restrict__ lb,
    const float* __restrict__ tk, const float* __restrict__ tv, const float* __restrict__ tr,
    unsigned short* __restrict__ ok, unsigned short* __restrict__ ov, unsigned short* __restrict__ orr)
{
    __shared__ float sred[4][4];
    const int m = blockIdx.x;
    const int t = m & (T_ - 1);
    const int tid = threadIdx.x;
    const int col0 = tid * 4;

    const float4 xc = *(const float4*)(xin + (size_t)m * C_ + col0);
    float4 xp = make_float4(0.f, 0.f, 0.f, 0.f);
    if (t > 0) xp = *(const float4*)(xin + (size_t)(m - 1) * C_ + col0);

    float s1 = xc.x + xc.y + xc.z + xc.w;
    float s2 = xc.x*xc.x + xc.y*xc.y + xc.z*xc.z + xc.w*xc.w;
    float s3 = xp.x + xp.y + xp.z + xp.w;
    float s4 = xp.x*xp.x + xp.y*xp.y + xp.z*xp.z + xp.w*xp.w;
    #pragma unroll
    for (int off = 32; off > 0; off >>= 1) {
        s1 += __shfl_down(s1, off);
        s2 += __shfl_down(s2, off);
        s3 += __shfl_down(s3, off);
        s4 += __shfl_down(s4, off);
    }
    const int wave = tid >> 6, lane = tid & 63;
    if (lane == 0) { sred[0][wave]=s1; sred[1][wave]=s2; sred[2][wave]=s3; sred[3][wave]=s4; }
    __syncthreads();
    const float S1 = sred[0][0]+sred[0][1]+sred[0][2]+sred[0][3];
    const float S2 = sred[1][0]+sred[1][1]+sred[1][2]+sred[1][3];
    const float S3 = sred[2][0]+sred[2][1]+sred[2][2]+sred[2][3];
    const float S4 = sred[3][0]+sred[3][1]+sred[3][2]+sred[3][3];

    const float inv = 1.0f / (float)C_;
    const float muc = S1 * inv;
    const float rc  = rsqrtf(S2 * inv - muc * muc + 1e-5f);
    const float mup = S3 * inv;
    const float rp  = rsqrtf(S4 * inv - mup * mup + 1e-5f);

    const float xcv[4] = {xc.x, xc.y, xc.z, xc.w};
    const float xpv[4] = {xp.x, xp.y, xp.z, xp.w};
    unsigned short rk[4], rv[4], rr[4];
    #pragma unroll
    for (int i = 0; i < 4; ++i) {
        const int col = col0 + i;
        const float w_ = lw[col], b_ = lb[col];
        const float h  = (xcv[i] - muc) * rc * w_ + b_;
        const float hh = (t > 0) ? (xpv[i] - mup) * rp * w_ + b_ : 0.f;
        const float ak = tk[col];
        rk[i] = f2bf(h * ak + hh * (1.f - ak));
        if (THREE) { const float av = tv[col]; rv[i] = f2bf(h * av + hh * (1.f - av)); }
        const float ar = tr[col];
        rr[i] = f2bf(h * ar + hh * (1.f - ar));
    }
    const size_t o = (size_t)m * C_ + col0;
    ushort4 u;
    u.x = rk[0]; u.y = rk[1]; u.z = rk[2]; u.w = rk[3];
    *(ushort4*)(ok + o) = u;
    if (THREE) {
        u.x = rv[0]; u.y = rv[1]; u.z = rv[2]; u.w = rv[3];
        *(ushort4*)(ov + o) = u;
    }
    u.x = rr[0]; u.y = rr[1]; u.z = rr[2]; u.w = rr[3];
    *(ushort4*)(orr + o) = u;
}

// ---------------------------------------------------------------------------
// WKV serial scan: one thread per (b,c). Inputs k,v,sr TRANSPOSED [b,c,t]
// (contiguous in t -> ushort8 vector loads + next-8 prefetch). Output p in
// normal [b,t,c] layout (coalesced per-wave stores, off critical path).
// ---------------------------------------------------------------------------
__global__ __launch_bounds__(64) void k_wkv(
    const unsigned short* __restrict__ kT, const unsigned short* __restrict__ vT,
    const unsigned short* __restrict__ sT,
    const float* __restrict__ tdec, const float* __restrict__ tfirst,
    unsigned short* __restrict__ p)
{
    const int g = blockIdx.x * 64 + threadIdx.x;   // 0..8191
    const int b = g >> 10;
    const int c = g & (C_ - 1);
    const float w = -__expf(tdec[c]);
    const float u = tfirst[c];
    const size_t tb = ((size_t)b * C_ + c) * T_;
    const unsigned short* kp = kT + tb;
    const unsigned short* vp = vT + tb;
    const unsigned short* sp = sT + tb;
    unsigned short* po = p + (size_t)b * T_ * C_ + c;

    float aa = 0.f, bb = 0.f, pp = -1e38f;
    ushort8 kq = *(const ushort8*)kp;
    ushort8 vq = *(const ushort8*)vp;
    ushort8 sq = *(const ushort8*)sp;
    for (int tt = 0; tt < T_; tt += 8) {
        ushort8 kn = kq, vn = vq, sn = sq;
        if (tt + 8 < T_) {
            kn = *(const ushort8*)(kp + tt + 8);
            vn = *(const ushort8*)(vp + tt + 8);
            sn = *(const ushort8*)(sp + tt + 8);
        }
        #pragma unroll
        for (int j = 0; j < 8; ++j) {
            const float kt = bf2f(kq[j]);
            const float vt = bf2f(vq[j]);
            float ww = u + kt;
            float qq = fmaxf(pp, ww);
            float e1 = __expf(pp - qq);
            float e2 = __expf(ww - qq);
            float y = (e1 * aa + e2 * vt) / (e1 * bb + e2);
            float ww2 = pp + w;
            float qq2 = fmaxf(ww2, kt);
            float e1b = __expf(ww2 - qq2);
            float e2b = __expf(kt - qq2);
            aa = e1b * aa + e2b * vt;
            bb = e1b * bb + e2b;
            pp = qq2;
            po[(size_t)(tt + j) * C_] = f2bf(bf2f(sq[j]) * y);
        }
        kq = kn; vq = vn; sq = sn;
    }
}

// ---------------------------------------------------------------------------
// bf16 MFMA GEMM: out[m,n] = sum_k A[m,k] * Bw[n,k]  (A ld=lda, Bw ld=ldb)
// 128x128 tile, 4 waves (2x2 of 64x64), BK=32, 16x16x32 MFMA,
// global_load_lds width=16 staging (wave w stages rows 32w..32w+31 of A and B).
// EPI: 0 = bf16 store; 1 = sigmoid->bf16; 2 = resid + acc -> fp32;
//      3 = relu(acc)^2 -> bf16; 4 = outF += bf16(mul)*acc (fp32 rmw)
// TRANS: bf16 output stored transposed [b, n, t] (only EPI 0/1).
// ---------------------------------------------------------------------------
template<int EPI, int TRANS>
__global__ __launch_bounds__(256) void k_gemm(
    const unsigned short* __restrict__ A, int lda,
    const unsigned short* __restrict__ Bw, int ldb,
    int K, int N,
    float* __restrict__ outF, unsigned short* __restrict__ outH,
    const float* __restrict__ resid, const unsigned short* __restrict__ mul)
{
    __shared__ unsigned short As[128 * 32];
    __shared__ unsigned short Bs[128 * 32];
    const int tid  = threadIdx.x;
    const int wave = tid >> 6, lane = tid & 63;
    const int quad = lane >> 4, l16 = lane & 15;
    const int m0 = blockIdx.x * 128, n0 = blockIdx.y * 128;
    const int wm = (wave >> 1) * 64, wn = (wave & 1) * 64;

    f32x4 acc[4][4];
    const f32x4 zero = {0.f, 0.f, 0.f, 0.f};
    #pragma unroll
    for (int i = 0; i < 4; ++i)
        #pragma unroll
        for (int j = 0; j < 4; ++j) acc[i][j] = zero;

    const int rw = 32 * wave;            // wave's staging row base
    const int rA = lane >> 2;            // 0..15 row within 16-row chunk
    const int c8 = (lane & 3) * 8;       // 0,8,16,24 (elements)

    const unsigned short* gA = A  + (size_t)(m0 + rw + rA) * lda + c8;
    const unsigned short* gB = Bw + (size_t)(n0 + rw + rA) * ldb + c8;
    unsigned short* lA0 = As + rw * 32;
    unsigned short* lA1 = As + (rw + 16) * 32;
    unsigned short* lB0 = Bs + rw * 32;
    unsigned short* lB1 = Bs + (rw + 16) * 32;

    for (int kt = 0; kt < K; kt += 32) {
        GLDS16(gA + kt,                     lA0);
        GLDS16(gA + kt + (size_t)16 * lda,  lA1);
        GLDS16(gB + kt,                     lB0);
        GLDS16(gB + kt + (size_t)16 * ldb,  lB1);
        __syncthreads();

        bf16x8 af[4], bfr[4];
        #pragma unroll
        for (int i = 0; i < 4; ++i) {
            af[i]  = *(const bf16x8*)(As + (wm + i * 16 + l16) * 32 + quad * 8);
            bfr[i] = *(const bf16x8*)(Bs + (wn + i * 16 + l16) * 32 + quad * 8);
        }
        #pragma unroll
        for (int i = 0; i < 4; ++i)
            #pragma unroll
            for (int j = 0; j < 4; ++j)
                acc[i][j] = __builtin_amdgcn_mfma_f32_16x16x32_bf16(af[i], bfr[j], acc[i][j], 0, 0, 0);
        __syncthreads();
    }

    // epilogue: C/D layout row = quad*4 + reg, col = l16
    #pragma unroll
    for (int i = 0; i < 4; ++i) {
        const int rowb = m0 + wm + i * 16 + quad * 4;
        if (TRANS) {
            const int b  = rowb >> 11;          // T_ = 2048
            const int t0 = rowb & (T_ - 1);     // 4 consecutive t per lane
            #pragma unroll
            for (int j = 0; j < 4; ++j) {
                const int col = n0 + wn + j * 16 + l16;
                ushort4 st;
                #pragma unroll
                for (int r = 0; r < 4; ++r) {
                    float v = acc[i][j][r];
                    if (EPI == 1) v = 1.f / (1.f + __expf(-v));
                    ((unsigned short*)&st)[r] = f2bf(v);
                }
                *(ushort4*)(outH + ((size_t)b * N + col) * T_ + t0) = st;
            }
        } else {
            #pragma unroll
            for (int j = 0; j < 4; ++j) {
                const int col = n0 + wn + j * 16 + l16;
                #pragma unroll
                for (int r = 0; r < 4; ++r) {
                    const size_t idx = (size_t)(rowb + r) * N + col;
                    const float v = acc[i][j][r];
                    if (EPI == 0)      outH[idx] = f2bf(v);
                    else if (EPI == 1) outH[idx] = f2bf(1.f / (1.f + __expf(-v)));
                    else if (EPI == 2) outF[idx] = resid[idx] + v;
                    else if (EPI == 3) { const float z = v > 0.f ? v : 0.f; outH[idx] = f2bf(z * z); }
                    else               outF[idx] = outF[idx] + bf2f(mul[idx]) * v;
                }
            }
        }
    }
}

// ---------------------------------------------------------------------------
// Workspace layout (peak 154 MB, every byte written before read each launch):
//   [0,32)MB    xk   -> vT   -> xk2
//   [32,64)     xv   -> p    -> tmp (FFN chunk)
//   [64,96)     xr   -> kT   -> xr2
//   [96,128)    srT  -> s2
//   [128,154)   bf16 weights (13M elems)
//   x1 lives in d_out (fp32), FFN chunks accumulate into d_out.
// ---------------------------------------------------------------------------
extern "C" void kernel_launch(void* const* d_in, const int* in_sizes, int n_in,
                              void* d_out, int out_size, void* d_ws, size_t ws_size,
                              hipStream_t stream)
{
    const float* x      = (const float*)d_in[0];
    const float* ln1w   = (const float*)d_in[1];
    const float* ln1b   = (const float*)d_in[2];
    const float* ln2w   = (const float*)d_in[3];
    const float* ln2b   = (const float*)d_in[4];
    const float* atk    = (const float*)d_in[5];
    const float* atv    = (const float*)d_in[6];
    const float* atr    = (const float*)d_in[7];
    const float* tdec   = (const float*)d_in[8];
    const float* tfirst = (const float*)d_in[9];
    const float* Wk     = (const float*)d_in[10];
    const float* Wv     = (const float*)d_in[11];
    const float* Wr     = (const float*)d_in[12];
    const float* Wo     = (const float*)d_in[13];
    const float* ftk    = (const float*)d_in[14];
    const float* ftr    = (const float*)d_in[15];
    const float* Wkey   = (const float*)d_in[16];
    const float* Wrec   = (const float*)d_in[17];
    const float* Wval   = (const float*)d_in[18];
    float* out = (float*)d_out;

    char* ws = (char*)d_ws;
    const size_t MB = 1ull << 20;
    unsigned short* xk  = (unsigned short*)(ws + 0 * MB);
    unsigned short* xv  = (unsigned short*)(ws + 32 * MB);
    unsigned short* xr  = (unsigned short*)(ws + 64 * MB);
    unsigned short* srT = (unsigned short*)(ws + 96 * MB);
    unsigned short* wb  = (unsigned short*)(ws + 128 * MB);
    unsigned short* kT  = xr;   // kT overwrites xr (dead after r-GEMM)
    unsigned short* vT  = xk;   // vT overwrites xk (dead after k-GEMM)
    unsigned short* p   = xv;   // p overwrites xv (dead after v-GEMM)
    unsigned short* xk2 = xk;
    unsigned short* xr2 = xr;
    unsigned short* s2  = srT;
    unsigned short* tmp = xv;   // FFN chunk buffer (p dead after Wo-GEMM)

    unsigned short* Wk_b   = wb;
    unsigned short* Wv_b   = wb + 1 * (1u << 20);
    unsigned short* Wr_b   = wb + 2 * (1u << 20);
    unsigned short* Wo_b   = wb + 3 * (1u << 20);
    unsigned short* Wrec_b = wb + 4 * (1u << 20);
    unsigned short* Wkey_b = wb + 5 * (1u << 20);
    unsigned short* Wval_b = wb + 9 * (1u << 20);

    // 1) weights -> bf16
    WSrc wsrc; wsrc.p[0]=Wk; wsrc.p[1]=Wv; wsrc.p[2]=Wr; wsrc.p[3]=Wo;
    wsrc.p[4]=Wrec; wsrc.p[5]=Wkey; wsrc.p[6]=Wval;
    k_convert<<<dim3(13312), dim3(256), 0, stream>>>(wsrc, wb);

    // 2) LN1 + time-shift mix -> xk, xv, xr (bf16)
    k_ln_mix<1><<<dim3(M_), dim3(256), 0, stream>>>(x, ln1w, ln1b, atk, atv, atr, xk, xv, xr);

    // 3) srT = sigmoid(xr @ Wr^T) [transposed], then kT, vT [transposed]
    k_gemm<1,1><<<dim3(128, 8), dim3(256), 0, stream>>>(xr, 1024, Wr_b, 1024, 1024, 1024, (float*)nullptr, srT, (const float*)nullptr, (const unsigned short*)nullptr);
    k_gemm<0,1><<<dim3(128, 8), dim3(256), 0, stream>>>(xk, 1024, Wk_b, 1024, 1024, 1024, (float*)nullptr, kT, (const float*)nullptr, (const unsigned short*)nullptr);
    k_gemm<0,1><<<dim3(128, 8), dim3(256), 0, stream>>>(xv, 1024, Wv_b, 1024, 1024, 1024, (float*)nullptr, vT, (const float*)nullptr, (const unsigned short*)nullptr);

    // 4) WKV scan (t-contiguous reads), fused p = sr * y (bf16, [b,t,c])
    k_wkv<<<dim3(128), dim3(64), 0, stream>>>(kT, vT, srT, tdec, tfirst, p);

    // 5) x1 = x + p @ Wo^T -> d_out (fp32)
    k_gemm<2,0><<<dim3(128, 8), dim3(256), 0, stream>>>(p, 1024, Wo_b, 1024, 1024, 1024, out, (unsigned short*)nullptr, x, (const unsigned short*)nullptr);

    // 6) LN2 + time-shift mix -> xk2, xr2 (bf16)
    k_ln_mix<0><<<dim3(M_), dim3(256), 0, stream>>>(out, ln2w, ln2b, ftk, (const float*)nullptr, ftr, xk2, (unsigned short*)nullptr, xr2);

    // 7) s2 = sigmoid(xr2 @ Wrec^T) (bf16, normal layout)
    k_gemm<1,0><<<dim3(128, 8), dim3(256), 0, stream>>>(xr2, 1024, Wrec_b, 1024, 1024, 1024, (float*)nullptr, s2, (const float*)nullptr, (const unsigned short*)nullptr);

    // 8) FFN chunked over F (4 x 1024): out += s2 * (relu(xk2@Wkey_f^T)^2 @ Wval_f^T)
    for (int f = 0; f < 4; ++f) {
        const unsigned short* WkeyF = Wkey_b + (size_t)f * 1024 * 1024;  // rows f*1024..
        const unsigned short* WvalF = Wval_b + (size_t)f * 1024;         // col offset, ld=4096
        k_gemm<3,0><<<dim3(128, 8), dim3(256), 0, stream>>>(xk2, 1024, WkeyF, 1024, 1024, 1024, (float*)nullptr, tmp, (const float*)nullptr, (const unsigned short*)nullptr);
        k_gemm<4,0><<<dim3(128, 8), dim3(256), 0, stream>>>(tmp, 1024, WvalF, 4096, 1024, 1024, out, (unsigned short*)nullptr, (const float*)nullptr, s2);
    }
}

// Round 4
// 1243.252 us; speedup vs baseline: 1.2750x; 1.1377x over previous
//
#include <hip/hip_runtime.h>
#include <stdint.h>

// RWKV-4 block: B=8, T=2048, C=1024, DIM_FFN=4096, fp32 in/out, bf16 MFMA internally.
#define B_ 8
#define T_ 2048
#define C_ 1024
#define F_ 4096
#define M_ (B_*T_)   // 16384 rows
#define NC 16        // WKV chunks per sequence
#define LCH (T_/NC)  // 128 steps per chunk

typedef __attribute__((ext_vector_type(8))) short bf16x8;   // MFMA A/B frag (4 VGPRs)
typedef __attribute__((ext_vector_type(4))) float f32x4;    // MFMA C/D frag

static __device__ __forceinline__ unsigned short f2bf(float f) {
    union { float f; unsigned u; } v; v.f = f;
    unsigned r = v.u + 0x7fffu + ((v.u >> 16) & 1u);  // RNE
    return (unsigned short)(r >> 16);
}
static __device__ __forceinline__ float bf2f(unsigned short h) {
    union { unsigned u; float f; } v; v.u = ((unsigned)h) << 16;
    return v.f;
}

// async global->LDS, 16B/lane, wave-uniform LDS base + lane*16 (m97 pattern)
#define GLDS16(gp, lp) __builtin_amdgcn_global_load_lds( \
    (const __attribute__((address_space(1))) unsigned int*)(gp), \
    (__attribute__((address_space(3))) unsigned int*)(lp), 16, 0, 0)

// ---------------------------------------------------------------------------
// Weight conversion fp32 -> bf16 into one packed ws region (13M elems, 26MB).
// dst element layout: [Wk 1M][Wv 1M][Wr 1M][Wo 1M][Wrec 1M][Wkey 4M][Wval 4M]
// ---------------------------------------------------------------------------
struct WSrc { const float* p[7]; };

__global__ __launch_bounds__(256) void k_convert(WSrc w, unsigned short* __restrict__ dst) {
    size_t e = ((size_t)blockIdx.x * 256 + threadIdx.x) * 4;
    int seg = (int)(e >> 20);
    const float* s; size_t off;
    if (seg < 5)      { s = w.p[seg]; off = e - ((size_t)seg << 20); }
    else if (seg < 9) { s = w.p[5];   off = e - (5ull << 20); }
    else              { s = w.p[6];   off = e - (9ull << 20); }
    float4 v = *(const float4*)(s + off);
    ushort4 o;
    o.x = f2bf(v.x); o.y = f2bf(v.y); o.z = f2bf(v.z); o.w = f2bf(v.w);
    *(ushort4*)(dst + e) = o;
}

// ---------------------------------------------------------------------------
// Fused LayerNorm + time_shift + token-mix. One block per row m = b*T+t.
// ---------------------------------------------------------------------------
template<int THREE>
__global__ __launch_bounds__(256) void k_ln_mix(
    const float* __restrict__ xin, const float* __restrict__ lw, const float* __restrict__ lb,
    const float* __restrict__ tk, const float* __restrict__ tv, const float* __restrict__ tr,
    unsigned short* __restrict__ ok, unsigned short* __restrict__ ov, unsigned short* __restrict__ orr)
{
    __shared__ float sred[4][4];
    const int m = blockIdx.x;
    const int t = m & (T_ - 1);
    const int tid = threadIdx.x;
    const int col0 = tid * 4;

    const float4 xc = *(const float4*)(xin + (size_t)m * C_ + col0);
    float4 xp = make_float4(0.f, 0.f, 0.f, 0.f);
    if (t > 0) xp = *(const float4*)(xin + (size_t)(m - 1) * C_ + col0);

    float s1 = xc.x + xc.y + xc.z + xc.w;
    float s2 = xc.x*xc.x + xc.y*xc.y + xc.z*xc.z + xc.w*xc.w;
    float s3 = xp.x + xp.y + xp.z + xp.w;
    float s4 = xp.x*xp.x + xp.y*xp.y + xp.z*xp.z + xp.w*xp.w;
    #pragma unroll
    for (int off = 32; off > 0; off >>= 1) {
        s1 += __shfl_down(s1, off);
        s2 += __shfl_down(s2, off);
        s3 += __shfl_down(s3, off);
        s4 += __shfl_down(s4, off);
    }
    const int wave = tid >> 6, lane = tid & 63;
    if (lane == 0) { sred[0][wave]=s1; sred[1][wave]=s2; sred[2][wave]=s3; sred[3][wave]=s4; }
    __syncthreads();
    const float S1 = sred[0][0]+sred[0][1]+sred[0][2]+sred[0][3];
    const float S2 = sred[1][0]+sred[1][1]+sred[1][2]+sred[1][3];
    const float S3 = sred[2][0]+sred[2][1]+sred[2][2]+sred[2][3];
    const float S4 = sred[3][0]+sred[3][1]+sred[3][2]+sred[3][3];

    const float inv = 1.0f / (float)C_;
    const float muc = S1 * inv;
    const float rc  = rsqrtf(S2 * inv - muc * muc + 1e-5f);
    const float mup = S3 * inv;
    const float rp  = rsqrtf(S4 * inv - mup * mup + 1e-5f);

    const float xcv[4] = {xc.x, xc.y, xc.z, xc.w};
    const float xpv[4] = {xp.x, xp.y, xp.z, xp.w};
    unsigned short rk[4], rv[4], rr[4];
    #pragma unroll
    for (int i = 0; i < 4; ++i) {
        const int col = col0 + i;
        const float w_ = lw[col], b_ = lb[col];
        const float h  = (xcv[i] - muc) * rc * w_ + b_;
        const float hh = (t > 0) ? (xpv[i] - mup) * rp * w_ + b_ : 0.f;
        const float ak = tk[col];
        rk[i] = f2bf(h * ak + hh * (1.f - ak));
        if (THREE) { const float av = tv[col]; rv[i] = f2bf(h * av + hh * (1.f - av)); }
        const float ar = tr[col];
        rr[i] = f2bf(h * ar + hh * (1.f - ar));
    }
    const size_t o = (size_t)m * C_ + col0;
    ushort4 u;
    u.x = rk[0]; u.y = rk[1]; u.z = rk[2]; u.w = rk[3];
    *(ushort4*)(ok + o) = u;
    if (THREE) {
        u.x = rv[0]; u.y = rv[1]; u.z = rv[2]; u.w = rv[3];
        *(ushort4*)(ov + o) = u;
    }
    u.x = rr[0]; u.y = rr[1]; u.z = rr[2]; u.w = rr[3];
    *(ushort4*)(orr + o) = u;
}

// ---------------------------------------------------------------------------
// WKV pass A: per (b,c,chunk) local state recurrence from zero init.
// Unnormalized recurrence A_t = e^w A_{t-1} + e^{kt} vt is linear in (A,B);
// we keep it max-normalized as (aa,bb,pp). Stores float4(aa,bb,pp,0).
// Thread map: c in low bits -> coalesced wave loads of k/v in [b,t,c].
// ---------------------------------------------------------------------------
__global__ __launch_bounds__(256) void k_wkv_local(
    const unsigned short* __restrict__ kb, const unsigned short* __restrict__ vb,
    const float* __restrict__ tdec, float4* __restrict__ st)
{
    const int g = blockIdx.x * 256 + threadIdx.x;   // 0..131071
    const int c = g & (C_ - 1);
    const int j = (g >> 10) & (NC - 1);
    const int b = g >> 14;
    const float w = -__expf(tdec[c]);
    float aa = 0.f, bb = 0.f, pp = -1e38f;
    const size_t base = ((size_t)(b * T_ + j * LCH)) * C_ + c;
    #pragma unroll 4
    for (int t = 0; t < LCH; ++t) {
        const float kt = bf2f(kb[base + (size_t)t * C_]);
        const float vt = bf2f(vb[base + (size_t)t * C_]);
        const float ww2 = pp + w;
        const float qq2 = fmaxf(ww2, kt);
        const float e1b = __expf(ww2 - qq2);
        const float e2b = __expf(kt - qq2);
        aa = e1b * aa + e2b * vt;
        bb = e1b * bb + e2b;
        pp = qq2;
    }
    st[((size_t)b * NC + j) * C_ + c] = make_float4(aa, bb, pp, 0.f);
}

// ---------------------------------------------------------------------------
// WKV pass C: build start state by combining preceding chunks' local states
// (log-sum-exp combine with e^{w*LCH} decay), then replay chunk computing
// y_t and p_t = sr_t * y_t.
// ---------------------------------------------------------------------------
__global__ __launch_bounds__(256) void k_wkv_scan(
    const unsigned short* __restrict__ kb, const unsigned short* __restrict__ vb,
    const unsigned short* __restrict__ sr,
    const float* __restrict__ tdec, const float* __restrict__ tfirst,
    const float4* __restrict__ st, unsigned short* __restrict__ p)
{
    const int g = blockIdx.x * 256 + threadIdx.x;
    const int c = g & (C_ - 1);
    const int j = (g >> 10) & (NC - 1);
    const int b = g >> 14;
    const float w = -__expf(tdec[c]);
    const float u = tfirst[c];

    // start state = combine of chunks 0..j-1 (j is wave-uniform)
    float aa = 0.f, bb = 0.f, pp = -1e38f;
    for (int i = 0; i < j; ++i) {
        const float4 s = st[((size_t)b * NC + i) * C_ + c];
        const float pdec = pp + w * (float)LCH;
        const float q  = fmaxf(pdec, s.z);
        const float eA = __expf(pdec - q);
        const float eB = __expf(s.z - q);
        aa = eA * aa + eB * s.x;
        bb = eA * bb + eB * s.y;
        pp = q;
    }

    const size_t base = ((size_t)(b * T_ + j * LCH)) * C_ + c;
    #pragma unroll 4
    for (int t = 0; t < LCH; ++t) {
        const size_t idx = base + (size_t)t * C_;
        const float kt = bf2f(kb[idx]);
        const float vt = bf2f(vb[idx]);
        const float ww = u + kt;
        const float qq = fmaxf(pp, ww);
        const float e1 = __expf(pp - qq);
        const float e2 = __expf(ww - qq);
        const float y  = (e1 * aa + e2 * vt) / (e1 * bb + e2);
        p[idx] = f2bf(bf2f(sr[idx]) * y);
        const float ww2 = pp + w;
        const float qq2 = fmaxf(ww2, kt);
        const float e1b = __expf(ww2 - qq2);
        const float e2b = __expf(kt - qq2);
        aa = e1b * aa + e2b * vt;
        bb = e1b * bb + e2b;
        pp = qq2;
    }
}

// ---------------------------------------------------------------------------
// Shared GEMM body: 128x128 tile, 4 waves (2x2 of 64x64), BK=32, 16x16x32
// MFMA, global_load_lds width=16 staging. Computes acc for (m0,n0).
// ---------------------------------------------------------------------------
static __device__ __forceinline__ void gemm_core(
    const unsigned short* __restrict__ A, int lda,
    const unsigned short* __restrict__ Bw, int ldb,
    int K, int m0, int n0,
    unsigned short* As, unsigned short* Bs, f32x4 acc[4][4])
{
    const int tid  = threadIdx.x;
    const int wave = tid >> 6, lane = tid & 63;
    const int quad = lane >> 4, l16 = lane & 15;
    const int wm = ((tid >> 6) >> 1) * 64, wn = ((tid >> 6) & 1) * 64;

    const int rw = 32 * wave;
    const int rA = lane >> 2;
    const int c8 = (lane & 3) * 8;

    const unsigned short* gA = A  + (size_t)(m0 + rw + rA) * lda + c8;
    const unsigned short* gB = Bw + (size_t)(n0 + rw + rA) * ldb + c8;
    unsigned short* lA0 = As + rw * 32;
    unsigned short* lA1 = As + (rw + 16) * 32;
    unsigned short* lB0 = Bs + rw * 32;
    unsigned short* lB1 = Bs + (rw + 16) * 32;

    for (int kt = 0; kt < K; kt += 32) {
        GLDS16(gA + kt,                     lA0);
        GLDS16(gA + kt + (size_t)16 * lda,  lA1);
        GLDS16(gB + kt,                     lB0);
        GLDS16(gB + kt + (size_t)16 * ldb,  lB1);
        __syncthreads();

        bf16x8 af[4], bfr[4];
        #pragma unroll
        for (int i = 0; i < 4; ++i) {
            af[i]  = *(const bf16x8*)(As + (wm + i * 16 + l16) * 32 + quad * 8);
            bfr[i] = *(const bf16x8*)(Bs + (wn + i * 16 + l16) * 32 + quad * 8);
        }
        #pragma unroll
        for (int i = 0; i < 4; ++i)
            #pragma unroll
            for (int j = 0; j < 4; ++j)
                acc[i][j] = __builtin_amdgcn_mfma_f32_16x16x32_bf16(af[i], bfr[j], acc[i][j], 0, 0, 0);
        __syncthreads();
    }
}

// Generic GEMM. EPI: 1 = sigmoid->bf16; 2 = resid + acc -> fp32;
//                3 = relu(acc)^2 -> bf16; 4 = outF += bf16(mul)*acc
template<int EPI>
__global__ __launch_bounds__(256) void k_gemm(
    const unsigned short* __restrict__ A, int lda,
    const unsigned short* __restrict__ Bw, int ldb,
    int K, int N,
    float* __restrict__ outF, unsigned short* __restrict__ outH,
    const float* __restrict__ resid, const unsigned short* __restrict__ mul)
{
    __shared__ unsigned short As[128 * 32];
    __shared__ unsigned short Bs[128 * 32];
    f32x4 acc[4][4];
    const f32x4 zero = {0.f, 0.f, 0.f, 0.f};
    #pragma unroll
    for (int i = 0; i < 4; ++i)
        #pragma unroll
        for (int j = 0; j < 4; ++j) acc[i][j] = zero;

    const int m0 = blockIdx.x * 128, n0 = blockIdx.y * 128;
    gemm_core(A, lda, Bw, ldb, K, m0, n0, As, Bs, acc);

    const int lane = threadIdx.x & 63, wave = threadIdx.x >> 6;
    const int quad = lane >> 4, l16 = lane & 15;
    const int wm = (wave >> 1) * 64, wn = (wave & 1) * 64;
    #pragma unroll
    for (int i = 0; i < 4; ++i) {
        const int rowb = m0 + wm + i * 16 + quad * 4;
        #pragma unroll
        for (int j = 0; j < 4; ++j) {
            const int col = n0 + wn + j * 16 + l16;
            #pragma unroll
            for (int r = 0; r < 4; ++r) {
                const size_t idx = (size_t)(rowb + r) * N + col;
                const float v = acc[i][j][r];
                if (EPI == 1)      outH[idx] = f2bf(1.f / (1.f + __expf(-v)));
                else if (EPI == 2) outF[idx] = resid[idx] + v;
                else if (EPI == 3) { const float z = v > 0.f ? v : 0.f; outH[idx] = f2bf(z * z); }
                else               outF[idx] = outF[idx] + bf2f(mul[idx]) * v;
            }
        }
    }
}

// Fused k/v/r projections: blockIdx.z selects input, weight, output, epilogue.
__global__ __launch_bounds__(256) void k_gemm_qkvr(
    const unsigned short* __restrict__ xk, const unsigned short* __restrict__ xv,
    const unsigned short* __restrict__ xr,
    const unsigned short* __restrict__ Wk, const unsigned short* __restrict__ Wv,
    const unsigned short* __restrict__ Wr,
    unsigned short* __restrict__ ok, unsigned short* __restrict__ ov,
    unsigned short* __restrict__ orr)
{
    __shared__ unsigned short As[128 * 32];
    __shared__ unsigned short Bs[128 * 32];
    const int z = blockIdx.z;
    const unsigned short* A  = (z == 0) ? xk : (z == 1) ? xv : xr;
    const unsigned short* Bw = (z == 0) ? Wk : (z == 1) ? Wv : Wr;
    unsigned short* outH     = (z == 0) ? ok : (z == 1) ? ov : orr;

    f32x4 acc[4][4];
    const f32x4 zero = {0.f, 0.f, 0.f, 0.f};
    #pragma unroll
    for (int i = 0; i < 4; ++i)
        #pragma unroll
        for (int j = 0; j < 4; ++j) acc[i][j] = zero;

    const int m0 = blockIdx.x * 128, n0 = blockIdx.y * 128;
    gemm_core(A, C_, Bw, C_, C_, m0, n0, As, Bs, acc);

    const int lane = threadIdx.x & 63, wave = threadIdx.x >> 6;
    const int quad = lane >> 4, l16 = lane & 15;
    const int wm = (wave >> 1) * 64, wn = (wave & 1) * 64;
    #pragma unroll
    for (int i = 0; i < 4; ++i) {
        const int rowb = m0 + wm + i * 16 + quad * 4;
        #pragma unroll
        for (int j = 0; j < 4; ++j) {
            const int col = n0 + wn + j * 16 + l16;
            #pragma unroll
            for (int r = 0; r < 4; ++r) {
                const size_t idx = (size_t)(rowb + r) * C_ + col;
                float v = acc[i][j][r];
                if (z == 2) v = 1.f / (1.f + __expf(-v));
                outH[idx] = f2bf(v);
            }
        }
    }
}

// ---------------------------------------------------------------------------
// Workspace layout (peak 154 MB):
//   [0,32)MB    xk   -> WKV states (2MB) -> xk2
//   [32,64)     xv   -> p    -> tmp (FFN chunk)
//   [64,96)     xr   -> xr2
//   [96,128)    sr   -> s2
//   [128,154)   bf16 weights (13M elems)
// k,v (bf16, 32MB each) live in d_out until step 5 overwrites it.
// ---------------------------------------------------------------------------
extern "C" void kernel_launch(void* const* d_in, const int* in_sizes, int n_in,
                              void* d_out, int out_size, void* d_ws, size_t ws_size,
                              hipStream_t stream)
{
    const float* x      = (const float*)d_in[0];
    const float* ln1w   = (const float*)d_in[1];
    const float* ln1b   = (const float*)d_in[2];
    const float* ln2w   = (const float*)d_in[3];
    const float* ln2b   = (const float*)d_in[4];
    const float* atk    = (const float*)d_in[5];
    const float* atv    = (const float*)d_in[6];
    const float* atr    = (const float*)d_in[7];
    const float* tdec   = (const float*)d_in[8];
    const float* tfirst = (const float*)d_in[9];
    const float* Wk     = (const float*)d_in[10];
    const float* Wv     = (const float*)d_in[11];
    const float* Wr     = (const float*)d_in[12];
    const float* Wo     = (const float*)d_in[13];
    const float* ftk    = (const float*)d_in[14];
    const float* ftr    = (const float*)d_in[15];
    const float* Wkey   = (const float*)d_in[16];
    const float* Wrec   = (const float*)d_in[17];
    const float* Wval   = (const float*)d_in[18];
    float* out = (float*)d_out;

    char* ws = (char*)d_ws;
    const size_t MB = 1ull << 20;
    unsigned short* xk  = (unsigned short*)(ws + 0 * MB);
    unsigned short* xv  = (unsigned short*)(ws + 32 * MB);
    unsigned short* xr  = (unsigned short*)(ws + 64 * MB);
    unsigned short* sr  = (unsigned short*)(ws + 96 * MB);
    unsigned short* wb  = (unsigned short*)(ws + 128 * MB);
    float4* states      = (float4*)(ws + 0 * MB);   // 2MB, xk dead after QKVR GEMM
    unsigned short* p   = xv;   // p overwrites xv (dead after QKVR GEMM)
    unsigned short* xk2 = xk;
    unsigned short* xr2 = xr;
    unsigned short* s2  = sr;
    unsigned short* tmp = xv;   // FFN chunk buffer (p dead after Wo-GEMM)
    unsigned short* kb  = (unsigned short*)d_out;            // 32MB
    unsigned short* vb  = (unsigned short*)d_out + (32*MB/2); // 32MB

    unsigned short* Wk_b   = wb;
    unsigned short* Wv_b   = wb + 1 * (1u << 20);
    unsigned short* Wr_b   = wb + 2 * (1u << 20);
    unsigned short* Wo_b   = wb + 3 * (1u << 20);
    unsigned short* Wrec_b = wb + 4 * (1u << 20);
    unsigned short* Wkey_b = wb + 5 * (1u << 20);
    unsigned short* Wval_b = wb + 9 * (1u << 20);

    // 1) weights -> bf16
    WSrc wsrc; wsrc.p[0]=Wk; wsrc.p[1]=Wv; wsrc.p[2]=Wr; wsrc.p[3]=Wo;
    wsrc.p[4]=Wrec; wsrc.p[5]=Wkey; wsrc.p[6]=Wval;
    k_convert<<<dim3(13312), dim3(256), 0, stream>>>(wsrc, wb);

    // 2) LN1 + time-shift mix -> xk, xv, xr (bf16)
    k_ln_mix<1><<<dim3(M_), dim3(256), 0, stream>>>(x, ln1w, ln1b, atk, atv, atr, xk, xv, xr);

    // 3) fused k/v/r projections: k->kb, v->vb, sr=sigmoid(r)->sr
    k_gemm_qkvr<<<dim3(128, 8, 3), dim3(256), 0, stream>>>(xk, xv, xr, Wk_b, Wv_b, Wr_b, kb, vb, sr);

    // 4) WKV: chunk-parallel scan (pass A: local states; pass C: replay + p)
    k_wkv_local<<<dim3(512), dim3(256), 0, stream>>>(kb, vb, tdec, states);
    k_wkv_scan<<<dim3(512), dim3(256), 0, stream>>>(kb, vb, sr, tdec, tfirst, states, p);

    // 5) x1 = x + p @ Wo^T -> d_out (fp32)
    k_gemm<2><<<dim3(128, 8), dim3(256), 0, stream>>>(p, 1024, Wo_b, 1024, 1024, 1024, out, (unsigned short*)nullptr, x, (const unsigned short*)nullptr);

    // 6) LN2 + time-shift mix -> xk2, xr2 (bf16)
    k_ln_mix<0><<<dim3(M_), dim3(256), 0, stream>>>(out, ln2w, ln2b, ftk, (const float*)nullptr, ftr, xk2, (unsigned short*)nullptr, xr2);

    // 7) s2 = sigmoid(xr2 @ Wrec^T) (bf16)
    k_gemm<1><<<dim3(128, 8), dim3(256), 0, stream>>>(xr2, 1024, Wrec_b, 1024, 1024, 1024, (float*)nullptr, s2, (const float*)nullptr, (const unsigned short*)nullptr);

    // 8) FFN chunked over F (4 x 1024): out += s2 * (relu(xk2@Wkey_f^T)^2 @ Wval_f^T)
    for (int f = 0; f < 4; ++f) {
        const unsigned short* WkeyF = Wkey_b + (size_t)f * 1024 * 1024;  // rows f*1024..
        const unsigned short* WvalF = Wval_b + (size_t)f * 1024;         // col offset, ld=4096
        k_gemm<3><<<dim3(128, 8), dim3(256), 0, stream>>>(xk2, 1024, WkeyF, 1024, 1024, 1024, (float*)nullptr, tmp, (const float*)nullptr, (const unsigned short*)nullptr);
        k_gemm<4><<<dim3(128, 8), dim3(256), 0, stream>>>(tmp, 1024, WvalF, 4096, 1024, 1024, out, (unsigned short*)nullptr, (const float*)nullptr, s2);
    }
}

// Round 5
// 1134.154 us; speedup vs baseline: 1.3976x; 1.0962x over previous
//
#include <hip/hip_runtime.h>
#include <stdint.h>

// RWKV-4 block: B=8, T=2048, C=1024, DIM_FFN=4096, fp32 in/out, bf16 MFMA internally.
#define B_ 8
#define T_ 2048
#define C_ 1024
#define F_ 4096
#define M_ (B_*T_)   // 16384 rows
#define NC 16        // WKV chunks per sequence
#define LCH (T_/NC)  // 128 steps per chunk

typedef __attribute__((ext_vector_type(8))) short bf16x8;   // MFMA A/B frag (4 VGPRs)
typedef __attribute__((ext_vector_type(4))) float f32x4;    // MFMA C/D frag

static __device__ __forceinline__ unsigned short f2bf(float f) {
    union { float f; unsigned u; } v; v.f = f;
    unsigned r = v.u + 0x7fffu + ((v.u >> 16) & 1u);  // RNE
    return (unsigned short)(r >> 16);
}
static __device__ __forceinline__ float bf2f(unsigned short h) {
    union { unsigned u; float f; } v; v.u = ((unsigned)h) << 16;
    return v.f;
}

// async global->LDS, 16B/lane, wave-uniform LDS base + lane*16 (m97 pattern)
#define GLDS16(gp, lp) __builtin_amdgcn_global_load_lds( \
    (const __attribute__((address_space(1))) unsigned int*)(gp), \
    (__attribute__((address_space(3))) unsigned int*)(lp), 16, 0, 0)

// ---------------------------------------------------------------------------
// Weight conversion fp32 -> bf16 into one packed ws region (13M elems, 26MB).
// dst element layout: [Wk 1M][Wv 1M][Wr 1M][Wo 1M][Wrec 1M][Wkey 4M][Wval 4M]
// ---------------------------------------------------------------------------
struct WSrc { const float* p[7]; };

__global__ __launch_bounds__(256) void k_convert(WSrc w, unsigned short* __restrict__ dst) {
    size_t e = ((size_t)blockIdx.x * 256 + threadIdx.x) * 4;
    int seg = (int)(e >> 20);
    const float* s; size_t off;
    if (seg < 5)      { s = w.p[seg]; off = e - ((size_t)seg << 20); }
    else if (seg < 9) { s = w.p[5];   off = e - (5ull << 20); }
    else              { s = w.p[6];   off = e - (9ull << 20); }
    float4 v = *(const float4*)(s + off);
    ushort4 o;
    o.x = f2bf(v.x); o.y = f2bf(v.y); o.z = f2bf(v.z); o.w = f2bf(v.w);
    *(ushort4*)(dst + e) = o;
}

// ---------------------------------------------------------------------------
// Fused LayerNorm + time_shift + token-mix. One block per row m = b*T+t.
// ---------------------------------------------------------------------------
template<int THREE>
__global__ __launch_bounds__(256) void k_ln_mix(
    const float* __restrict__ xin, const float* __restrict__ lw, const float* __restrict__ lb,
    const float* __restrict__ tk, const float* __restrict__ tv, const float* __restrict__ tr,
    unsigned short* __restrict__ ok, unsigned short* __restrict__ ov, unsigned short* __restrict__ orr)
{
    __shared__ float sred[4][4];
    const int m = blockIdx.x;
    const int t = m & (T_ - 1);
    const int tid = threadIdx.x;
    const int col0 = tid * 4;

    const float4 xc = *(const float4*)(xin + (size_t)m * C_ + col0);
    float4 xp = make_float4(0.f, 0.f, 0.f, 0.f);
    if (t > 0) xp = *(const float4*)(xin + (size_t)(m - 1) * C_ + col0);

    float s1 = xc.x + xc.y + xc.z + xc.w;
    float s2 = xc.x*xc.x + xc.y*xc.y + xc.z*xc.z + xc.w*xc.w;
    float s3 = xp.x + xp.y + xp.z + xp.w;
    float s4 = xp.x*xp.x + xp.y*xp.y + xp.z*xp.z + xp.w*xp.w;
    #pragma unroll
    for (int off = 32; off > 0; off >>= 1) {
        s1 += __shfl_down(s1, off);
        s2 += __shfl_down(s2, off);
        s3 += __shfl_down(s3, off);
        s4 += __shfl_down(s4, off);
    }
    const int wave = tid >> 6, lane = tid & 63;
    if (lane == 0) { sred[0][wave]=s1; sred[1][wave]=s2; sred[2][wave]=s3; sred[3][wave]=s4; }
    __syncthreads();
    const float S1 = sred[0][0]+sred[0][1]+sred[0][2]+sred[0][3];
    const float S2 = sred[1][0]+sred[1][1]+sred[1][2]+sred[1][3];
    const float S3 = sred[2][0]+sred[2][1]+sred[2][2]+sred[2][3];
    const float S4 = sred[3][0]+sred[3][1]+sred[3][2]+sred[3][3];

    const float inv = 1.0f / (float)C_;
    const float muc = S1 * inv;
    const float rc  = rsqrtf(S2 * inv - muc * muc + 1e-5f);
    const float mup = S3 * inv;
    const float rp  = rsqrtf(S4 * inv - mup * mup + 1e-5f);

    const float xcv[4] = {xc.x, xc.y, xc.z, xc.w};
    const float xpv[4] = {xp.x, xp.y, xp.z, xp.w};
    unsigned short rk[4], rv[4], rr[4];
    #pragma unroll
    for (int i = 0; i < 4; ++i) {
        const int col = col0 + i;
        const float w_ = lw[col], b_ = lb[col];
        const float h  = (xcv[i] - muc) * rc * w_ + b_;
        const float hh = (t > 0) ? (xpv[i] - mup) * rp * w_ + b_ : 0.f;
        const float ak = tk[col];
        rk[i] = f2bf(h * ak + hh * (1.f - ak));
        if (THREE) { const float av = tv[col]; rv[i] = f2bf(h * av + hh * (1.f - av)); }
        const float ar = tr[col];
        rr[i] = f2bf(h * ar + hh * (1.f - ar));
    }
    const size_t o = (size_t)m * C_ + col0;
    ushort4 u;
    u.x = rk[0]; u.y = rk[1]; u.z = rk[2]; u.w = rk[3];
    *(ushort4*)(ok + o) = u;
    if (THREE) {
        u.x = rv[0]; u.y = rv[1]; u.z = rv[2]; u.w = rv[3];
        *(ushort4*)(ov + o) = u;
    }
    u.x = rr[0]; u.y = rr[1]; u.z = rr[2]; u.w = rr[3];
    *(ushort4*)(orr + o) = u;
}

// ---------------------------------------------------------------------------
// WKV pass A: per (b,c,chunk) local state recurrence from zero init.
// ---------------------------------------------------------------------------
__global__ __launch_bounds__(256) void k_wkv_local(
    const unsigned short* __restrict__ kb, const unsigned short* __restrict__ vb,
    const float* __restrict__ tdec, float4* __restrict__ st)
{
    const int g = blockIdx.x * 256 + threadIdx.x;   // 0..131071
    const int c = g & (C_ - 1);
    const int j = (g >> 10) & (NC - 1);
    const int b = g >> 14;
    const float w = -__expf(tdec[c]);
    float aa = 0.f, bb = 0.f, pp = -1e38f;
    const size_t base = ((size_t)(b * T_ + j * LCH)) * C_ + c;
    #pragma unroll 4
    for (int t = 0; t < LCH; ++t) {
        const float kt = bf2f(kb[base + (size_t)t * C_]);
        const float vt = bf2f(vb[base + (size_t)t * C_]);
        const float ww2 = pp + w;
        const float qq2 = fmaxf(ww2, kt);
        const float e1b = __expf(ww2 - qq2);
        const float e2b = __expf(kt - qq2);
        aa = e1b * aa + e2b * vt;
        bb = e1b * bb + e2b;
        pp = qq2;
    }
    st[((size_t)b * NC + j) * C_ + c] = make_float4(aa, bb, pp, 0.f);
}

// ---------------------------------------------------------------------------
// WKV pass C: combine preceding chunk states, replay chunk computing p=sr*y.
// ---------------------------------------------------------------------------
__global__ __launch_bounds__(256) void k_wkv_scan(
    const unsigned short* __restrict__ kb, const unsigned short* __restrict__ vb,
    const unsigned short* __restrict__ sr,
    const float* __restrict__ tdec, const float* __restrict__ tfirst,
    const float4* __restrict__ st, unsigned short* __restrict__ p)
{
    const int g = blockIdx.x * 256 + threadIdx.x;
    const int c = g & (C_ - 1);
    const int j = (g >> 10) & (NC - 1);
    const int b = g >> 14;
    const float w = -__expf(tdec[c]);
    const float u = tfirst[c];

    float aa = 0.f, bb = 0.f, pp = -1e38f;
    for (int i = 0; i < j; ++i) {
        const float4 s = st[((size_t)b * NC + i) * C_ + c];
        const float pdec = pp + w * (float)LCH;
        const float q  = fmaxf(pdec, s.z);
        const float eA = __expf(pdec - q);
        const float eB = __expf(s.z - q);
        aa = eA * aa + eB * s.x;
        bb = eA * bb + eB * s.y;
        pp = q;
    }

    const size_t base = ((size_t)(b * T_ + j * LCH)) * C_ + c;
    #pragma unroll 4
    for (int t = 0; t < LCH; ++t) {
        const size_t idx = base + (size_t)t * C_;
        const float kt = bf2f(kb[idx]);
        const float vt = bf2f(vb[idx]);
        const float ww = u + kt;
        const float qq = fmaxf(pp, ww);
        const float e1 = __expf(pp - qq);
        const float e2 = __expf(ww - qq);
        const float y  = (e1 * aa + e2 * vt) / (e1 * bb + e2);
        p[idx] = f2bf(bf2f(sr[idx]) * y);
        const float ww2 = pp + w;
        const float qq2 = fmaxf(ww2, kt);
        const float e1b = __expf(ww2 - qq2);
        const float e2b = __expf(kt - qq2);
        aa = e1b * aa + e2b * vt;
        bb = e1b * bb + e2b;
        pp = qq2;
    }
}

// ---------------------------------------------------------------------------
// Shared GEMM core: 128x128 tile, 4 waves (2x2 of 64x64), BK=64, 16x16x32
// MFMA, global_load_lds width=16 staging, XOR-swizzled LDS: 16B block q of
// row r stored at physical block q^(r&7) -> frag reads hit 8 distinct banks
// per 16-lane phase (2-way = free). LDS row = 64 ushorts (128 B), 32 KB total.
// K must be a multiple of 64.
// ---------------------------------------------------------------------------
static __device__ __forceinline__ void gemm_core(
    const unsigned short* __restrict__ A, int lda,
    const unsigned short* __restrict__ Bw, int ldb,
    int K, int m0, int n0,
    unsigned short* As, unsigned short* Bs, f32x4 acc[4][4])
{
    const int tid  = threadIdx.x;
    const int wave = tid >> 6, lane = tid & 63;
    const int quad = lane >> 4, l16 = lane & 15;
    const int wm = (wave >> 1) * 64, wn = (wave & 1) * 64;

    const int rw  = wave * 32;            // wave's 32-row staging band
    const int r8  = lane >> 3;            // 0..7 row within an 8-row issue
    const int csrc = ((lane & 7) ^ r8) * 8;  // swizzled SOURCE 16B-block

    const unsigned short* gA = A  + (size_t)(m0 + rw + r8) * lda + csrc;
    const unsigned short* gB = Bw + (size_t)(n0 + rw + r8) * ldb + csrc;

    const int pa = l16 & 7;               // read-side swizzle term

    for (int kt = 0; kt < K; kt += 64) {
        #pragma unroll
        for (int ii = 0; ii < 4; ++ii) {
            GLDS16(gA + kt + (size_t)(ii * 8) * lda, As + (rw + ii * 8) * 64);
            GLDS16(gB + kt + (size_t)(ii * 8) * ldb, Bs + (rw + ii * 8) * 64);
        }
        __syncthreads();

        #pragma unroll
        for (int h = 0; h < 2; ++h) {
            const int pq = ((h * 4 + quad) ^ pa) * 8;
            bf16x8 af[4], bfr[4];
            #pragma unroll
            for (int i = 0; i < 4; ++i) {
                af[i]  = *(const bf16x8*)(As + (wm + i * 16 + l16) * 64 + pq);
                bfr[i] = *(const bf16x8*)(Bs + (wn + i * 16 + l16) * 64 + pq);
            }
            #pragma unroll
            for (int i = 0; i < 4; ++i)
                #pragma unroll
                for (int j = 0; j < 4; ++j)
                    acc[i][j] = __builtin_amdgcn_mfma_f32_16x16x32_bf16(af[i], bfr[j], acc[i][j], 0, 0, 0);
        }
        __syncthreads();
    }
}

// Generic GEMM. EPI: 1 = sigmoid->bf16; 2 = resid + acc -> fp32;
//                3 = relu(acc)^2 -> bf16; 4 = outF += bf16(mul)*acc
template<int EPI>
__global__ __launch_bounds__(256) void k_gemm(
    const unsigned short* __restrict__ A, int lda,
    const unsigned short* __restrict__ Bw, int ldb,
    int K, int N,
    float* __restrict__ outF, unsigned short* __restrict__ outH,
    const float* __restrict__ resid, const unsigned short* __restrict__ mul)
{
    __shared__ unsigned short As[128 * 64];
    __shared__ unsigned short Bs[128 * 64];
    f32x4 acc[4][4];
    const f32x4 zero = {0.f, 0.f, 0.f, 0.f};
    #pragma unroll
    for (int i = 0; i < 4; ++i)
        #pragma unroll
        for (int j = 0; j < 4; ++j) acc[i][j] = zero;

    const int m0 = blockIdx.x * 128, n0 = blockIdx.y * 128;
    gemm_core(A, lda, Bw, ldb, K, m0, n0, As, Bs, acc);

    const int lane = threadIdx.x & 63, wave = threadIdx.x >> 6;
    const int quad = lane >> 4, l16 = lane & 15;
    const int wm = (wave >> 1) * 64, wn = (wave & 1) * 64;
    #pragma unroll
    for (int i = 0; i < 4; ++i) {
        const int rowb = m0 + wm + i * 16 + quad * 4;
        #pragma unroll
        for (int j = 0; j < 4; ++j) {
            const int col = n0 + wn + j * 16 + l16;
            #pragma unroll
            for (int r = 0; r < 4; ++r) {
                const size_t idx = (size_t)(rowb + r) * N + col;
                const float v = acc[i][j][r];
                if (EPI == 1)      outH[idx] = f2bf(1.f / (1.f + __expf(-v)));
                else if (EPI == 2) outF[idx] = resid[idx] + v;
                else if (EPI == 3) { const float z = v > 0.f ? v : 0.f; outH[idx] = f2bf(z * z); }
                else               outF[idx] = outF[idx] + bf2f(mul[idx]) * v;
            }
        }
    }
}

// Fused k/v/r projection: one dispatch vs packed [Wk;Wv;Wr] (N=3072).
// n-segment (n0>>10, uniform per block) selects BOTH the A input (xk/xv/xr)
// and the output (k->ok, v->ov, sigmoid(r)->orr).
__global__ __launch_bounds__(256) void k_gemm_kvr(
    const unsigned short* __restrict__ xk, const unsigned short* __restrict__ xv,
    const unsigned short* __restrict__ xr,
    const unsigned short* __restrict__ W3,
    unsigned short* __restrict__ ok, unsigned short* __restrict__ ov,
    unsigned short* __restrict__ orr)
{
    __shared__ unsigned short As[128 * 64];
    __shared__ unsigned short Bs[128 * 64];
    f32x4 acc[4][4];
    const f32x4 zero = {0.f, 0.f, 0.f, 0.f};
    #pragma unroll
    for (int i = 0; i < 4; ++i)
        #pragma unroll
        for (int j = 0; j < 4; ++j) acc[i][j] = zero;

    const int m0 = blockIdx.x * 128, n0 = blockIdx.y * 128;
    const int seg = n0 >> 10;                       // 0=k 1=v 2=r
    const unsigned short* A = (seg == 0) ? xk : (seg == 1) ? xv : xr;
    unsigned short* outH    = (seg == 0) ? ok : (seg == 1) ? ov : orr;

    gemm_core(A, C_, W3, C_, C_, m0, n0, As, Bs, acc);

    const int nl0 = n0 & (C_ - 1);
    const int lane = threadIdx.x & 63, wave = threadIdx.x >> 6;
    const int quad = lane >> 4, l16 = lane & 15;
    const int wm = (wave >> 1) * 64, wn = (wave & 1) * 64;
    #pragma unroll
    for (int i = 0; i < 4; ++i) {
        const int rowb = m0 + wm + i * 16 + quad * 4;
        #pragma unroll
        for (int j = 0; j < 4; ++j) {
            const int col = nl0 + wn + j * 16 + l16;
            #pragma unroll
            for (int r = 0; r < 4; ++r) {
                const size_t idx = (size_t)(rowb + r) * C_ + col;
                float v = acc[i][j][r];
                if (seg == 2) v = 1.f / (1.f + __expf(-v));
                outH[idx] = f2bf(v);
            }
        }
    }
}

// ---------------------------------------------------------------------------
// Workspace layout (peak 154 MB):
//   [0,32)MB    xk   -> WKV states (2MB) -> xk2
//   [32,64)     xv   -> p    -> tmp (FFN chunk)
//   [64,96)     xr   -> xr2
//   [96,128)    sr   -> s2
//   [128,154)   bf16 weights ([Wk;Wv;Wr] contiguous for fused GEMM)
// k,v (bf16, 32MB each) live in d_out until step 5 overwrites it.
// ---------------------------------------------------------------------------
extern "C" void kernel_launch(void* const* d_in, const int* in_sizes, int n_in,
                              void* d_out, int out_size, void* d_ws, size_t ws_size,
                              hipStream_t stream)
{
    const float* x      = (const float*)d_in[0];
    const float* ln1w   = (const float*)d_in[1];
    const float* ln1b   = (const float*)d_in[2];
    const float* ln2w   = (const float*)d_in[3];
    const float* ln2b   = (const float*)d_in[4];
    const float* atk    = (const float*)d_in[5];
    const float* atv    = (const float*)d_in[6];
    const float* atr    = (const float*)d_in[7];
    const float* tdec   = (const float*)d_in[8];
    const float* tfirst = (const float*)d_in[9];
    const float* Wk     = (const float*)d_in[10];
    const float* Wv     = (const float*)d_in[11];
    const float* Wr     = (const float*)d_in[12];
    const float* Wo     = (const float*)d_in[13];
    const float* ftk    = (const float*)d_in[14];
    const float* ftr    = (const float*)d_in[15];
    const float* Wkey   = (const float*)d_in[16];
    const float* Wrec   = (const float*)d_in[17];
    const float* Wval   = (const float*)d_in[18];
    float* out = (float*)d_out;

    char* ws = (char*)d_ws;
    const size_t MB = 1ull << 20;
    unsigned short* xk  = (unsigned short*)(ws + 0 * MB);
    unsigned short* xv  = (unsigned short*)(ws + 32 * MB);
    unsigned short* xr  = (unsigned short*)(ws + 64 * MB);
    unsigned short* sr  = (unsigned short*)(ws + 96 * MB);
    unsigned short* wb  = (unsigned short*)(ws + 128 * MB);
    float4* states      = (float4*)(ws + 0 * MB);   // 2MB, xk dead after kvr GEMM
    unsigned short* p   = xv;   // p overwrites xv (dead after kvr GEMM)
    unsigned short* xk2 = xk;
    unsigned short* xr2 = xr;
    unsigned short* s2  = sr;
    unsigned short* tmp = xv;   // FFN chunk buffer (p dead after Wo-GEMM)
    unsigned short* kb  = (unsigned short*)d_out;             // 32MB
    unsigned short* vb  = (unsigned short*)d_out + (32*MB/2); // 32MB

    unsigned short* W3_b   = wb;                   // [Wk;Wv;Wr] 3072x1024
    unsigned short* Wo_b   = wb + 3 * (1u << 20);
    unsigned short* Wrec_b = wb + 4 * (1u << 20);
    unsigned short* Wkey_b = wb + 5 * (1u << 20);
    unsigned short* Wval_b = wb + 9 * (1u << 20);

    // 1) weights -> bf16
    WSrc wsrc; wsrc.p[0]=Wk; wsrc.p[1]=Wv; wsrc.p[2]=Wr; wsrc.p[3]=Wo;
    wsrc.p[4]=Wrec; wsrc.p[5]=Wkey; wsrc.p[6]=Wval;
    k_convert<<<dim3(13312), dim3(256), 0, stream>>>(wsrc, wb);

    // 2) LN1 + time-shift mix -> xk, xv, xr (bf16)
    k_ln_mix<1><<<dim3(M_), dim3(256), 0, stream>>>(x, ln1w, ln1b, atk, atv, atr, xk, xv, xr);

    // 3) fused k/v/r projections (N=3072): k->kb, v->vb, sigmoid(r)->sr
    k_gemm_kvr<<<dim3(128, 24), dim3(256), 0, stream>>>(xk, xv, xr, W3_b, kb, vb, sr);

    // 4) WKV: chunk-parallel scan
    k_wkv_local<<<dim3(512), dim3(256), 0, stream>>>(kb, vb, tdec, states);
    k_wkv_scan<<<dim3(512), dim3(256), 0, stream>>>(kb, vb, sr, tdec, tfirst, states, p);

    // 5) x1 = x + p @ Wo^T -> d_out (fp32)
    k_gemm<2><<<dim3(128, 8), dim3(256), 0, stream>>>(p, 1024, Wo_b, 1024, 1024, 1024, out, (unsigned short*)nullptr, x, (const unsigned short*)nullptr);

    // 6) LN2 + time-shift mix -> xk2, xr2 (bf16)
    k_ln_mix<0><<<dim3(M_), dim3(256), 0, stream>>>(out, ln2w, ln2b, ftk, (const float*)nullptr, ftr, xk2, (unsigned short*)nullptr, xr2);

    // 7) s2 = sigmoid(xr2 @ Wrec^T) (bf16)
    k_gemm<1><<<dim3(128, 8), dim3(256), 0, stream>>>(xr2, 1024, Wrec_b, 1024, 1024, 1024, (float*)nullptr, s2, (const float*)nullptr, (const unsigned short*)nullptr);

    // 8) FFN chunked over F (4 x 1024): out += s2 * (relu(xk2@Wkey_f^T)^2 @ Wval_f^T)
    for (int f = 0; f < 4; ++f) {
        const unsigned short* WkeyF = Wkey_b + (size_t)f * 1024 * 1024;
        const unsigned short* WvalF = Wval_b + (size_t)f * 1024;
        k_gemm<3><<<dim3(128, 8), dim3(256), 0, stream>>>(xk2, 1024, WkeyF, 1024, 1024, 1024, (float*)nullptr, tmp, (const float*)nullptr, (const unsigned short*)nullptr);
        k_gemm<4><<<dim3(128, 8), dim3(256), 0, stream>>>(tmp, 1024, WvalF, 4096, 1024, 1024, out, (unsigned short*)nullptr, (const float*)nullptr, s2);
    }
}